// Round 16
// baseline (389.881 us; speedup 1.0000x reference)
//
#include <hip/hip_runtime.h>
#include <hip/hip_bf16.h>
#include <math.h>

// ---------------------------------------------------------------------------
// GATGNN global attention:  softmax_seg( MLP([x|glbl]) )  on MI355X (gfx950)
// R16: 256x256 / 8-wave / BK=32 GEMMs with ring-4 LDS and 4-phase fine
//      interleave + counted vmcnt(4) (T3+T4 ledger-verified):
//      phase = {stage 1 half-tile (kt+2) | ds_read new frags | lgkm0+schedbar
//               | setprio 8xMFMA}, barrier per phase, never drain vmcnt to 0
//      except the last two K-tiles. Proven chunk-XOR swizzle (0 conflicts).
// ---------------------------------------------------------------------------

#define NSEG 1024

typedef __attribute__((ext_vector_type(8))) short short8;
typedef __attribute__((ext_vector_type(4))) float f32x4;

__device__ __forceinline__ unsigned short f2bf(float f) {
  __hip_bfloat16 h = __float2bfloat16(f);
  return *reinterpret_cast<unsigned short*>(&h);
}
__device__ __forceinline__ float softplus_fast(float z) {
  float t = __expf(-fabsf(z));
  return fmaxf(z, 0.f) + __logf(1.f + t);
}
__device__ __forceinline__ void gll16(const void* g, void* l) {
  __builtin_amdgcn_global_load_lds(
      (const __attribute__((address_space(1))) void*)g,
      (__attribute__((address_space(3))) void*)l, 16, 0, 0);
}
// m204 bijective XCD-chunked swizzle (works for nwg % 8 != 0).
__device__ __forceinline__ int xcd_swz(int bid, int nwg) {
  int q = nwg >> 3, r = nwg & 7, x = bid & 7, i = bid >> 3;
  return (x < r ? x * (q + 1) : r * (q + 1) + (x - r) * q) + i;
}

// ---------------------------------------------------------------------------
// prep: W0 [620,512] -> W0T bf16 [512,640] (K-pad 0); W1 -> W1T [512,512].
// ---------------------------------------------------------------------------
__global__ __launch_bounds__(256) void prep(const float* __restrict__ W0,
                                            const float* __restrict__ W1,
                                            unsigned short* __restrict__ W0T,
                                            unsigned short* __restrict__ W1T) {
  int t = blockIdx.x * 256 + threadIdx.x;
  if (t < 512 * 640) {
    int n = t / 640, k = t % 640;
    W0T[t] = f2bf(k < 620 ? W0[(size_t)k * 512 + n] : 0.f);
    return;
  }
  t -= 512 * 640;
  if (t < 512 * 512) {
    int n = t / 512, k = t % 512;
    W1T[t] = f2bf(W1[(size_t)k * 512 + n]);
  }
}

// ---------------------------------------------------------------------------
// pack (grid-stride, 2048 blocks): x -> X16 [Mp,512] bf16; gx -> G16 [Mp,128]
// bf16 (cols>=108 zero); zero logits. Pad rows (>=N) zeroed.
// ---------------------------------------------------------------------------
__global__ __launch_bounds__(256) void pack(const float* __restrict__ x,
                                            const float* __restrict__ gx,
                                            unsigned short* __restrict__ X16,
                                            unsigned short* __restrict__ G16,
                                            float* __restrict__ logits,
                                            int N, int Mp) {
  const int total = Mp * 80 + (Mp >> 2);
  for (int t = blockIdx.x * 256 + threadIdx.x; t < total; t += gridDim.x * 256) {
    union { unsigned short u[8]; uint4 q; } v;
    if (t < Mp * 64) {                      // X16
      int row = t >> 6, c = t & 63;
      if (row >= N) {
#pragma unroll
        for (int j = 0; j < 8; ++j) v.u[j] = 0;
      } else {
        const float4* p = (const float4*)(x + (size_t)row * 512 + c * 8);
        float4 a = p[0], b = p[1];
        v.u[0] = f2bf(a.x); v.u[1] = f2bf(a.y); v.u[2] = f2bf(a.z); v.u[3] = f2bf(a.w);
        v.u[4] = f2bf(b.x); v.u[5] = f2bf(b.y); v.u[6] = f2bf(b.z); v.u[7] = f2bf(b.w);
      }
      *reinterpret_cast<uint4*>(X16 + (size_t)row * 512 + c * 8) = v.q;
    } else if (t < Mp * 80) {               // G16
      int t2 = t - Mp * 64;
      int row = t2 >> 4, c = t2 & 15;
#pragma unroll
      for (int j = 0; j < 8; ++j) {
        int col = c * 8 + j;
        v.u[j] = (row < N && col < 108) ? f2bf(gx[(size_t)row * 108 + col]) : 0;
      }
      *reinterpret_cast<uint4*>(G16 + (size_t)row * 128 + c * 8) = v.q;
    } else {                                // logits zero (float4)
      int i = (t - Mp * 80) << 2;
      *reinterpret_cast<float4*>(logits + i) = float4{0.f, 0.f, 0.f, 0.f};
    }
  }
}

// ---------------------------------------------------------------------------
// gemm8p: Z[M,512] = A[M,K]*WT^T + bias, 256x256 tile, BK=32, 8 waves (2x4),
// 128x64 per wave, mfma(w,a) swapped.
//   LDS: ring-4 K-tile slots x 2 M-halves per operand (4*2*8KB*2 = 128KB).
//   Half-tile = 128 rows x 32 cols bf16 = 8KB = 1 gll16/thread.
//   Iter kt (K-tile): 4 phases (C-quadrants). Phase p: stage half p of
//   K-tile kt+2 -> slot (kt+2)&3; barrier; ds_read new frags; lgkm0 +
//   sched_barrier; setprio(1); 8 MFMA; setprio(0).
//   vmcnt(4) at phase 0 (kt < KT-2): in-flight = kt+1's 4 halves exactly
//   => K-tile kt fully landed, loads span barriers. Tail iters: vmcnt(0).
//   Overwrite safety: slot (kt+2)&3 holds kt-2, read-complete 2 iters ago.
//  SPLITA: A = [A1 stride 512 | A2 stride 128], k-boundary 512.
//  FUSE=false: C = bf16(softplus(Z));  FUSE=true: logits += softplus(Z)*W2.
// ---------------------------------------------------------------------------
template <int K, bool SPLITA, bool FUSE>
__global__ __launch_bounds__(512, 2) void gemm8p(const unsigned short* __restrict__ A1,
                                                 const unsigned short* __restrict__ A2,
                                                 const unsigned short* __restrict__ WT,
                                                 const float* __restrict__ bias,
                                                 unsigned short* __restrict__ C,
                                                 const float* __restrict__ W2,
                                                 float* __restrict__ logits, int nwg) {
  constexpr int KT = K / 32;
  __shared__ unsigned short Ab[4][2][128 * 32];   // [slot][half][r*32+c] 64KB
  __shared__ unsigned short Bb[4][2][128 * 32];   // 64KB
  const int L = xcd_swz(blockIdx.x, nwg);
  const int nt = L & 1, mt = L >> 1;              // N=512 -> 2 col tiles of 256
  const int tid = threadIdx.x, lane = tid & 63, wid = tid >> 6;
  const int wm = wid >> 2, wn = wid & 3, bh = wn >> 1;
  const int lm = lane & 15, rch = lane >> 4;
  const int wrow = (wn & 1) * 64;                 // local row base in B-half

  // staging decode: thread -> (row, chunk-slot); source pre-swizzled
  const int sr = tid >> 2, scs = tid & 3;
  const int sch = (scs ^ ((sr >> 1) & 3)) << 3;   // source chunk col (elems)

  f32x4 acc[8][4] = {};

  auto stage_half = [&](int slot, int ktile, int h) {
    const int k = ktile * 32 + sch;
    if (h < 2) {
      const int row = mt * 256 + h * 128 + sr;
      const unsigned short* src;
      if constexpr (SPLITA) {
        src = (k < 512) ? A1 + (size_t)row * 512 + k
                        : A2 + (size_t)row * 128 + (k - 512);
      } else {
        src = A1 + (size_t)row * 512 + k;
      }
      gll16(src, &Ab[slot][h][tid * 8]);
    } else {
      const int row = nt * 256 + (h - 2) * 128 + sr;
      gll16(WT + (size_t)row * K + k, &Bb[slot][h - 2][tid * 8]);
    }
  };

  short8 af[4], wf[2];
  auto read_af = [&](int slot, int mibase) {
#pragma unroll
    for (int i = 0; i < 4; ++i) {
      int rw = (mibase + i) * 16 + lm;
      af[i] = *reinterpret_cast<const short8*>(
          &Ab[slot][wm][rw * 32 + ((rch ^ ((rw >> 1) & 3)) << 3)]);
    }
  };
  auto read_wf = [&](int slot, int nibase) {
#pragma unroll
    for (int i = 0; i < 2; ++i) {
      int rw = wrow + (nibase + i) * 16 + lm;
      wf[i] = *reinterpret_cast<const short8*>(
          &Bb[slot][bh][rw * 32 + ((rch ^ ((rw >> 1) & 3)) << 3)]);
    }
  };
  auto mfma8 = [&](int mibase, int nibase) {
    asm volatile("s_waitcnt lgkmcnt(0)" ::: "memory");
    __builtin_amdgcn_sched_barrier(0);           // rule #18: pin MFMA after wait
    __builtin_amdgcn_s_setprio(1);
#pragma unroll
    for (int i = 0; i < 4; ++i)
#pragma unroll
      for (int j = 0; j < 2; ++j)
        acc[mibase + i][nibase + j] = __builtin_amdgcn_mfma_f32_16x16x32_bf16(
            wf[j], af[i], acc[mibase + i][nibase + j], 0, 0, 0);
    __builtin_amdgcn_s_setprio(0);
  };

  // prologue: K-tiles 0,1 fully staged (8 loads/thread in flight)
#pragma unroll
  for (int h = 0; h < 4; ++h) stage_half(0, 0, h);
#pragma unroll
  for (int h = 0; h < 4; ++h) stage_half(1, 1, h);

  for (int kt = 0; kt < KT; ++kt) {
    const int slot = kt & 3, sst = (kt + 2) & 3;
    const bool st = (kt + 2) < KT;
    // ---- phase 0: Q(mh0, nh0) ----
    if (kt < KT - 2) asm volatile("s_waitcnt vmcnt(4)" ::: "memory");
    else             asm volatile("s_waitcnt vmcnt(0)" ::: "memory");
    if (st) stage_half(sst, kt + 2, 0);
    __builtin_amdgcn_s_barrier();
    read_af(slot, 0);
    read_wf(slot, 0);
    mfma8(0, 0);
    // ---- phase 1: Q(mh0, nh1) ----
    if (st) stage_half(sst, kt + 2, 1);
    __builtin_amdgcn_s_barrier();
    read_wf(slot, 2);
    mfma8(0, 2);
    // ---- phase 2: Q(mh1, nh1) ----
    if (st) stage_half(sst, kt + 2, 2);
    __builtin_amdgcn_s_barrier();
    read_af(slot, 4);
    mfma8(4, 2);
    // ---- phase 3: Q(mh1, nh0) ----
    if (st) stage_half(sst, kt + 2, 3);
    __builtin_amdgcn_s_barrier();
    read_wf(slot, 0);
    mfma8(4, 0);
  }

  // epilogue: thread holds C[m][n0..n0+3]
  //   m  = mt*256 + wm*128 + mi*16 + lm ; n0 = nt*256 + wn*64 + ni*16 + rch*4
#pragma unroll
  for (int mi = 0; mi < 8; ++mi) {
    const int m = mt * 256 + wm * 128 + mi * 16 + lm;
    float part = 0.f;
#pragma unroll
    for (int ni = 0; ni < 4; ++ni) {
      const int n0 = nt * 256 + wn * 64 + ni * 16 + (rch << 2);
      const f32x4 bb = *reinterpret_cast<const f32x4*>(bias + n0);
      f32x4 v = acc[mi][ni];
      if constexpr (!FUSE) {
        union { unsigned short u[4]; uint2 qv; } o;
#pragma unroll
        for (int rr = 0; rr < 4; ++rr) o.u[rr] = f2bf(softplus_fast(v[rr] + bb[rr]));
        *reinterpret_cast<uint2*>(C + (size_t)m * 512 + n0) = o.qv;
      } else {
        const f32x4 wv = *reinterpret_cast<const f32x4*>(W2 + n0);
#pragma unroll
        for (int rr = 0; rr < 4; ++rr) part += softplus_fast(v[rr] + bb[rr]) * wv[rr];
      }
    }
    if constexpr (FUSE) {
      part += __shfl_xor(part, 16);
      part += __shfl_xor(part, 32);
      if (lane < 16) atomicAdd(logits + m, part);
    }
  }
}

// ---------------------------------------------------------------------------
// Per-segment softmax: one block per segment; batch sorted -> binary search.
// (b2 omitted: softmax is shift-invariant.)
// ---------------------------------------------------------------------------
__global__ __launch_bounds__(256) void segsoftmax(const float* __restrict__ logits,
                                                  const int* __restrict__ batch,
                                                  float* __restrict__ out, int N) {
  const int g = blockIdx.x;
  const int tid = threadIdx.x;
  int lo = 0, hi = N;
  while (lo < hi) { int mid = (lo + hi) >> 1; if (batch[mid] < g) lo = mid + 1; else hi = mid; }
  const int beg = lo;
  hi = N;
  while (lo < hi) { int mid = (lo + hi) >> 1; if (batch[mid] < g + 1) lo = mid + 1; else hi = mid; }
  const int end = lo;
  if (beg >= end) return;

  __shared__ float sh[4];
  float m = -INFINITY;
  for (int i = beg + tid; i < end; i += 256) m = fmaxf(m, logits[i]);
#pragma unroll
  for (int o = 32; o; o >>= 1) m = fmaxf(m, __shfl_down(m, o));
  if ((tid & 63) == 0) sh[tid >> 6] = m;
  __syncthreads();
  m = fmaxf(fmaxf(sh[0], sh[1]), fmaxf(sh[2], sh[3]));
  __syncthreads();

  float s = 0.f;
  for (int i = beg + tid; i < end; i += 256) s += expf(logits[i] - m);
#pragma unroll
  for (int o = 32; o; o >>= 1) s += __shfl_down(s, o);
  if ((tid & 63) == 0) sh[tid >> 6] = s;
  __syncthreads();
  s = sh[0] + sh[1] + sh[2] + sh[3];

  const float inv = 1.f / (s + 1e-16f);
  for (int i = beg + tid; i < end; i += 256) out[i] = expf(logits[i] - m) * inv;
}

// ---------------------------------------------------------------------------
extern "C" void kernel_launch(void* const* d_in, const int* in_sizes, int n_in,
                              void* d_out, int out_size, void* d_ws, size_t ws_size,
                              hipStream_t stream) {
  const float* x = (const float*)d_in[0];
  const int* batch = (const int*)d_in[1];
  const float* gx = (const float*)d_in[2];
  const float* W0 = (const float*)d_in[3];
  const float* b0 = (const float*)d_in[4];
  const float* W1 = (const float*)d_in[5];
  const float* b1 = (const float*)d_in[6];
  const float* W2 = (const float*)d_in[7];
  float* out = (float*)d_out;

  const int N = in_sizes[1];                 // 100000
  const int Mp = ((N + 255) / 256) * 256;    // 100096 = 256*391
  const int nwg = (Mp / 256) * 2;            // 782 blocks per GEMM

  auto align256 = [](size_t v) { return (v + 255) & ~(size_t)255; };
  char* ws = (char*)d_ws;
  size_t off = 0;
  unsigned short* X16 = (unsigned short*)(ws + off); off = align256(off + (size_t)Mp * 512 * 2);
  unsigned short* G16 = (unsigned short*)(ws + off); off = align256(off + (size_t)Mp * 128 * 2);
  unsigned short* W0T = (unsigned short*)(ws + off); off = align256(off + (size_t)512 * 640 * 2);
  unsigned short* W1T = (unsigned short*)(ws + off); off = align256(off + (size_t)512 * 512 * 2);
  unsigned short* H0 = (unsigned short*)(ws + off);  off = align256(off + (size_t)Mp * 512 * 2);
  float* logits = (float*)(ws + off);                off = align256(off + (size_t)Mp * 4);
  (void)ws_size; (void)n_in; (void)out_size;

  const int prep_elems = 512 * 640 + 512 * 512;
  prep<<<(prep_elems + 255) / 256, 256, 0, stream>>>(W0, W1, W0T, W1T);
  pack<<<2048, 256, 0, stream>>>(x, gx, X16, G16, logits, N, Mp);

  gemm8p<640, true, false><<<nwg, 512, 0, stream>>>(X16, G16, W0T, b0, H0,
                                                    nullptr, nullptr, nwg);
  gemm8p<512, false, true><<<nwg, 512, 0, stream>>>(H0, nullptr, W1T, b1,
                                                    nullptr, W2, logits, nwg);

  segsoftmax<<<NSEG, 256, 0, stream>>>(logits, batch, out, N);
}